// Round 1
// baseline (80.377 us; speedup 1.0000x reference)
//
#include <hip/hip_runtime.h>
#include <math.h>

// FilteredCrossEntropyLoss: B=1048576 rows, C=64 classes.
// loss = (1/B) * sum_rows [ sum_j w_j*log(w_j) + lse(pred_row) - sum_j w_j*pred[idx_j] ]
// (every filter sums to 1.0, so the lse coefficient is exactly 1)
//
// Layout: each 16-lane group owns one row (16 lanes x float4 = 64 cols).
// One wave = 4 rows/iteration; 4-step shfl_xor butterflies within groups.

#define THREADS 256
#define WAVES_PER_BLOCK 4
#define NBLOCKS 2048

__global__ __launch_bounds__(THREADS, 8)
void fce_main(const float* __restrict__ pred, const int* __restrict__ target,
              float* __restrict__ partial, int ngroups,
              float K0, float K1, float K62, float K63, float Ke) {
    const int lane = threadIdx.x & 63;
    const int wid  = threadIdx.x >> 6;
    const int gwave = blockIdx.x * WAVES_PER_BLOCK + wid;
    const int nwaves = gridDim.x * WAVES_PER_BLOCK;
    const int sub  = lane >> 4;      // which of the 4 rows in this wave-iter
    const int l16  = lane & 15;      // lane within 16-group
    const int cbase = l16 * 4;       // first column this lane covers

    float acc = 0.0f;

    for (int g = gwave; g < ngroups; g += nwaves) {
        const int row = g * 4 + sub;
        const float4 p4 = *reinterpret_cast<const float4*>(
            pred + (size_t)g * 256 + (size_t)lane * 4);
        const int t = target[row];

        float p[4] = {p4.x, p4.y, p4.z, p4.w};

        // ---- group max (for a faithful max-subtracted log-softmax) ----
        float mx = fmaxf(fmaxf(p[0], p[1]), fmaxf(p[2], p[3]));
        #pragma unroll
        for (int m = 1; m < 16; m <<= 1)
            mx = fmaxf(mx, __shfl_xor(mx, m));

        // ---- per-column filter weights ----
        // else branch: weight at column c is filt[|j-2|] with j=(c-t+37)&63
        float w[4];
        #pragma unroll
        for (int k = 0; k < 4; ++k) {
            const int c = cbase + k;
            const int j = (c - t + 37) & 63;
            const int j2 = j - 2;
            const int d = (j2 < 0) ? -j2 : j2;
            w[k] = (d == 0) ? 0.34f : (d == 1) ? 0.23f : (d == 2) ? 0.10f : 0.0f;
        }
        const bool edge = (t < 2) | (t >= 62);
        if (__any(edge)) {   // wave-uniform branch; ~22% of wave-iters
            const int tt = (t >= 62) ? (63 - t) : t;   // mirror to {0,1}
            #pragma unroll
            for (int k = 0; k < 4; ++k) {
                const int c  = cbase + k;
                const int cc = (t >= 62) ? (63 - c) : c;
                const float w0 = (cc == 0) ? 0.60f : (cc == 1) ? 0.25f
                               : (cc == 2) ? 0.15f : 0.0f;
                const float w1 = (cc == 0) ? 0.25f : (cc == 1) ? 0.40f
                               : (cc == 2) ? 0.25f : (cc == 3) ? 0.10f : 0.0f;
                const float we = (tt == 0) ? w0 : w1;
                if (edge) w[k] = we;
            }
        }

        // ---- exp-sum and weighted-pred sum, combined butterfly ----
        float esum = 0.0f, wp = 0.0f;
        #pragma unroll
        for (int k = 0; k < 4; ++k) {
            esum += __expf(p[k] - mx);
            wp = fmaf(w[k], p[k], wp);
        }
        #pragma unroll
        for (int m = 1; m < 16; m <<= 1) {
            esum += __shfl_xor(esum, m);
            wp   += __shfl_xor(wp, m);
        }

        const float lse = mx + __logf(esum);
        const float K = (t == 0) ? K0 : (t == 1) ? K1
                      : (t == 62) ? K62 : (t == 63) ? K63 : Ke;
        acc += K + lse - wp;   // identical across the 16-lane group
    }

    // wave total: groups hold identical values within themselves, so just
    // combine the 4 groups (xor 16, 32) -> every lane has the wave sum.
    acc += __shfl_xor(acc, 16);
    acc += __shfl_xor(acc, 32);

    __shared__ float sacc[WAVES_PER_BLOCK];
    if (lane == 0) sacc[wid] = acc;
    __syncthreads();
    if (threadIdx.x == 0) {
        float s = 0.0f;
        #pragma unroll
        for (int i = 0; i < WAVES_PER_BLOCK; ++i) s += sacc[i];
        partial[blockIdx.x] = s;
    }
}

__global__ __launch_bounds__(THREADS)
void fce_reduce(const float* __restrict__ partial, int n,
                float* __restrict__ out, float invB) {
    float s = 0.0f;
    for (int i = threadIdx.x; i < n; i += THREADS) s += partial[i];
    #pragma unroll
    for (int m = 1; m < 64; m <<= 1) s += __shfl_xor(s, m);
    __shared__ float ws[WAVES_PER_BLOCK];
    const int wid = threadIdx.x >> 6;
    if ((threadIdx.x & 63) == 0) ws[wid] = s;
    __syncthreads();
    if (threadIdx.x == 0) {
        float tot = 0.0f;
        #pragma unroll
        for (int i = 0; i < WAVES_PER_BLOCK; ++i) tot += ws[i];
        out[0] = tot * invB;
    }
}

extern "C" void kernel_launch(void* const* d_in, const int* in_sizes, int n_in,
                              void* d_out, int out_size, void* d_ws, size_t ws_size,
                              hipStream_t stream) {
    const float* pred  = (const float*)d_in[0];
    const int* target  = (const int*)d_in[1];
    float* partial     = (float*)d_ws;
    float* out         = (float*)d_out;

    const int B = in_sizes[1];       // 1048576 rows
    const int ngroups = B / 4;       // 4 rows per wave-iteration

    // sum_j w_j * log(w_j) per filter type (host-computed, exact)
    const float K0  = 0.60f*logf(0.60f) + 0.25f*logf(0.25f) + 0.15f*logf(0.15f);
    const float K1  = 0.25f*logf(0.25f) + 0.40f*logf(0.40f)
                    + 0.25f*logf(0.25f) + 0.10f*logf(0.10f);
    const float K62 = K1;            // mirrored filter, same entropy
    const float K63 = K0;
    const float Ke  = 2.0f*0.10f*logf(0.10f) + 2.0f*0.23f*logf(0.23f)
                    + 0.34f*logf(0.34f);

    fce_main<<<NBLOCKS, THREADS, 0, stream>>>(pred, target, partial, ngroups,
                                              K0, K1, K62, K63, Ke);
    fce_reduce<<<1, THREADS, 0, stream>>>(partial, NBLOCKS, out, 1.0f / (float)B);
}